// Round 1
// baseline (902.884 us; speedup 1.0000x reference)
//
#include <hip/hip_runtime.h>
#include <math.h>

#define NSEQ 2048
#define CDIM 768
#define NH   12
#define HD   64
#define NB   2

// ---------------------------------------------------------------------------
// Kernel 1: qkv = X @ Wqkv^T ; fused scale (q), RoPE (q,k), head transpose.
// X: [4096, 768], Wqkv: [2304, 768]. Writes Q,K,V as [B, H, N, 64] fp32.
// Tiles 128x128x32, 256 threads, 8x8 microtile, tx-skewed LDS reads.
// ---------------------------------------------------------------------------
__global__ __launch_bounds__(256)
void qkv_rope_kernel(const float* __restrict__ X, const float* __restrict__ W,
                     float* __restrict__ Qb, float* __restrict__ Kb,
                     float* __restrict__ Vb)
{
    __shared__ float As[128 * 32];
    __shared__ float Bs[128 * 32];
    const int tid = threadIdx.x;
    const int tx = tid & 15, ty = tid >> 4;
    const int m0 = blockIdx.x * 128;
    const int n0 = blockIdx.y * 128;

    float acc[8][8];
#pragma unroll
    for (int i = 0; i < 8; ++i)
#pragma unroll
        for (int j = 0; j < 8; ++j) acc[i][j] = 0.f;

    for (int kt = 0; kt < CDIM; kt += 32) {
        __syncthreads();
#pragma unroll
        for (int it = 0; it < 4; ++it) {
            int idx = tid + 256 * it;          // 0..1023
            int row = idx >> 3;                // 0..127
            int c4  = (idx & 7) << 2;          // 0..28
            *(float4*)&As[row * 32 + c4] =
                *(const float4*)&X[(size_t)(m0 + row) * CDIM + kt + c4];
            *(float4*)&Bs[row * 32 + c4] =
                *(const float4*)&W[(size_t)(n0 + row) * CDIM + kt + c4];
        }
        __syncthreads();
        const float4* As4 = (const float4*)As;
        const float4* Bs4 = (const float4*)Bs;
#pragma unroll
        for (int kq = 0; kq < 8; ++kq) {
            const int ke = (kq + tx) & 7;      // skew: spread LDS banks across tx
            float4 a[8], b[8];
#pragma unroll
            for (int i = 0; i < 8; ++i) a[i] = As4[(ty * 8 + i) * 8 + ke];
#pragma unroll
            for (int j = 0; j < 8; ++j) b[j] = Bs4[(tx * 8 + j) * 8 + ke];
#pragma unroll
            for (int i = 0; i < 8; ++i)
#pragma unroll
                for (int j = 0; j < 8; ++j) {
                    acc[i][j] = fmaf(a[i].x, b[j].x, acc[i][j]);
                    acc[i][j] = fmaf(a[i].y, b[j].y, acc[i][j]);
                    acc[i][j] = fmaf(a[i].z, b[j].z, acc[i][j]);
                    acc[i][j] = fmaf(a[i].w, b[j].w, acc[i][j]);
                }
        }
    }

    // Epilogue: block-uniform q/k/v selector (768 = 6*128, no tile straddle).
    const int nb  = n0 + tx * 8;
    const int sel = nb / CDIM;       // 0=q, 1=k, 2=v (uniform over block)
    const int rem = nb % CDIM;
    const int h   = rem >> 6;
    const int dd  = rem & 63;        // 8-aligned -> RoPE pairs within thread

    float* dst = (sel == 0) ? Qb : (sel == 1) ? Kb : Vb;
    const float scl = (sel == 0) ? 0.125f : 1.0f;   // d^-0.5, q only

    float invf[4];
    if (sel < 2) {
        // inv_freq[e/2] = 10000^(-e/64) = exp(-ln(1e4)/64 * e)
#pragma unroll
        for (int p = 0; p < 4; ++p)
            invf[p] = expf(-0.14391156831212787f * (float)(dd + 2 * p));
    }

#pragma unroll
    for (int i = 0; i < 8; ++i) {
        int m  = m0 + ty * 8 + i;
        int bi = m >> 11;            // /2048
        int nn = m & 2047;
        size_t base = (((size_t)(bi * NH + h)) * NSEQ + nn) * HD + dd;
        if (sel == 2) {
            *(float4*)&dst[base] =
                make_float4(acc[i][0], acc[i][1], acc[i][2], acc[i][3]);
            *(float4*)&dst[base + 4] =
                make_float4(acc[i][4], acc[i][5], acc[i][6], acc[i][7]);
        } else {
            float o[8];
            float fn = (float)nn;
#pragma unroll
            for (int p = 0; p < 4; ++p) {
                float ang = fn * invf[p];    // bit-identical to np fp32 product
                float sv = sinf(ang), cv = cosf(ang);
                float e0 = acc[i][2 * p]     * scl;
                float e1 = acc[i][2 * p + 1] * scl;
                o[2 * p]     = e0 * cv - e1 * sv;
                o[2 * p + 1] = e1 * cv + e0 * sv;
            }
            *(float4*)&dst[base]     = make_float4(o[0], o[1], o[2], o[3]);
            *(float4*)&dst[base + 4] = make_float4(o[4], o[5], o[6], o[7]);
        }
    }
}

// ---------------------------------------------------------------------------
// Kernel 2: flash attention, fp32. One WG per (b*h, 64-row q tile).
// 64x64 S tiles, 4x4 micro, online softmax (in-wave width-16 shuffles),
// P via LDS into a second 4x4-micro GEMM against V. Writes [B, N, C].
// ---------------------------------------------------------------------------
__global__ __launch_bounds__(256)
void attn_kernel(const float* __restrict__ Qb, const float* __restrict__ Kb,
                 const float* __restrict__ Vb, float* __restrict__ AO)
{
    __shared__ float Qs[64 * 64];
    __shared__ float Ks[64 * 64];
    __shared__ float Vs[64 * 64];
    __shared__ float Ps[64 * 64];
    const int tid = threadIdx.x, tx = tid & 15, ty = tid >> 4;
    const int qt = blockIdx.x;    // 0..31
    const int bh = blockIdx.y;    // 0..23
    const float* Qg = Qb + ((size_t)bh * NSEQ + qt * 64) * HD;
    const float* Kg = Kb + (size_t)bh * NSEQ * HD;
    const float* Vg = Vb + (size_t)bh * NSEQ * HD;

#pragma unroll
    for (int it = 0; it < 4; ++it) {
        int idx = tid + 256 * it;
        int row = idx >> 4, c4 = (idx & 15) << 2;
        *(float4*)&Qs[row * 64 + c4] = *(const float4*)&Qg[row * 64 + c4];
    }

    float m_i[4], l_i[4], O[4][4];
#pragma unroll
    for (int i = 0; i < 4; ++i) {
        m_i[i] = -1e30f;  // finite sentinel: avoids inf-inf NaN on first tile
        l_i[i] = 0.f;
#pragma unroll
        for (int j = 0; j < 4; ++j) O[i][j] = 0.f;
    }

    for (int kt = 0; kt < NSEQ / 64; ++kt) {
        __syncthreads();   // protects Ps/Vs of previous iter, Qs on first
#pragma unroll
        for (int it = 0; it < 4; ++it) {
            int idx = tid + 256 * it;
            int row = idx >> 4, c4 = (idx & 15) << 2;
            *(float4*)&Ks[row * 64 + c4] =
                *(const float4*)&Kg[(size_t)(kt * 64 + row) * HD + c4];
            *(float4*)&Vs[row * 64 + c4] =
                *(const float4*)&Vg[(size_t)(kt * 64 + row) * HD + c4];
        }
        __syncthreads();

        // S = Q_tile . K_tile^T
        float s[4][4];
#pragma unroll
        for (int i = 0; i < 4; ++i)
#pragma unroll
            for (int j = 0; j < 4; ++j) s[i][j] = 0.f;
        const float4* Qs4 = (const float4*)Qs;
        const float4* Ks4 = (const float4*)Ks;
#pragma unroll
        for (int kq = 0; kq < 16; ++kq) {
            const int ke = (kq + tx) & 15;
            float4 a[4], b[4];
#pragma unroll
            for (int i = 0; i < 4; ++i) a[i] = Qs4[(ty * 4 + i) * 16 + ke];
#pragma unroll
            for (int j = 0; j < 4; ++j) b[j] = Ks4[(tx * 4 + j) * 16 + ke];
#pragma unroll
            for (int i = 0; i < 4; ++i)
#pragma unroll
                for (int j = 0; j < 4; ++j) {
                    s[i][j] = fmaf(a[i].x, b[j].x, s[i][j]);
                    s[i][j] = fmaf(a[i].y, b[j].y, s[i][j]);
                    s[i][j] = fmaf(a[i].z, b[j].z, s[i][j]);
                    s[i][j] = fmaf(a[i].w, b[j].w, s[i][j]);
                }
        }

        // online softmax per q-row (rows owned by ty-group; reduce over tx)
        float alpha[4];
#pragma unroll
        for (int i = 0; i < 4; ++i) {
            float mt = fmaxf(fmaxf(s[i][0], s[i][1]), fmaxf(s[i][2], s[i][3]));
            mt = fmaxf(mt, __shfl_xor(mt, 1));
            mt = fmaxf(mt, __shfl_xor(mt, 2));
            mt = fmaxf(mt, __shfl_xor(mt, 4));
            mt = fmaxf(mt, __shfl_xor(mt, 8));
            float mn = fmaxf(m_i[i], mt);
            alpha[i] = __expf(m_i[i] - mn);
            m_i[i] = mn;
            float rs = 0.f;
#pragma unroll
            for (int j = 0; j < 4; ++j) {
                float p = __expf(s[i][j] - mn);
                s[i][j] = p;
                rs += p;
            }
            rs += __shfl_xor(rs, 1);
            rs += __shfl_xor(rs, 2);
            rs += __shfl_xor(rs, 4);
            rs += __shfl_xor(rs, 8);
            l_i[i] = l_i[i] * alpha[i] + rs;
        }

        float4* Ps4w = (float4*)Ps;
#pragma unroll
        for (int i = 0; i < 4; ++i)
            Ps4w[(ty * 4 + i) * 16 + tx] =
                make_float4(s[i][0], s[i][1], s[i][2], s[i][3]);
        __syncthreads();

#pragma unroll
        for (int i = 0; i < 4; ++i)
#pragma unroll
            for (int j = 0; j < 4; ++j) O[i][j] *= alpha[i];

        // O += P . V   (dot over key dim, 4 keys per float4)
        const float4* Ps4 = (const float4*)Ps;
        const float4* Vs4 = (const float4*)Vs;
#pragma unroll
        for (int cq = 0; cq < 16; ++cq) {
            const int ce = (cq + tx) & 15;
            float4 p4[4], v4[4];
#pragma unroll
            for (int i = 0; i < 4; ++i) p4[i] = Ps4[(ty * 4 + i) * 16 + ce];
#pragma unroll
            for (int u = 0; u < 4; ++u) v4[u] = Vs4[(ce * 4 + u) * 16 + tx];
#pragma unroll
            for (int i = 0; i < 4; ++i) {
                O[i][0] = fmaf(p4[i].x, v4[0].x, O[i][0]);
                O[i][0] = fmaf(p4[i].y, v4[1].x, O[i][0]);
                O[i][0] = fmaf(p4[i].z, v4[2].x, O[i][0]);
                O[i][0] = fmaf(p4[i].w, v4[3].x, O[i][0]);
                O[i][1] = fmaf(p4[i].x, v4[0].y, O[i][1]);
                O[i][1] = fmaf(p4[i].y, v4[1].y, O[i][1]);
                O[i][1] = fmaf(p4[i].z, v4[2].y, O[i][1]);
                O[i][1] = fmaf(p4[i].w, v4[3].y, O[i][1]);
                O[i][2] = fmaf(p4[i].x, v4[0].z, O[i][2]);
                O[i][2] = fmaf(p4[i].y, v4[1].z, O[i][2]);
                O[i][2] = fmaf(p4[i].z, v4[2].z, O[i][2]);
                O[i][2] = fmaf(p4[i].w, v4[3].z, O[i][2]);
                O[i][3] = fmaf(p4[i].x, v4[0].w, O[i][3]);
                O[i][3] = fmaf(p4[i].y, v4[1].w, O[i][3]);
                O[i][3] = fmaf(p4[i].z, v4[2].w, O[i][3]);
                O[i][3] = fmaf(p4[i].w, v4[3].w, O[i][3]);
            }
        }
    }

    // normalize and store to [B, N, C] (head-interleaved, ready for proj GEMM)
    const int b = bh / NH, h = bh % NH;
#pragma unroll
    for (int i = 0; i < 4; ++i) {
        float inv = 1.0f / l_i[i];
        size_t row = (size_t)b * NSEQ + qt * 64 + ty * 4 + i;
        *(float4*)&AO[row * CDIM + h * HD + tx * 4] =
            make_float4(O[i][0] * inv, O[i][1] * inv,
                        O[i][2] * inv, O[i][3] * inv);
    }
}

// ---------------------------------------------------------------------------
// Kernel 3: out = AO @ Wproj^T + bias. AO: [4096,768], Wproj: [768,768].
// Tiles 128x64x32, 256 threads, 8x4 microtile.
// ---------------------------------------------------------------------------
__global__ __launch_bounds__(256)
void proj_kernel(const float* __restrict__ A, const float* __restrict__ W,
                 const float* __restrict__ bias, float* __restrict__ out)
{
    __shared__ float As[128 * 32];
    __shared__ float Bs[64 * 32];
    const int tid = threadIdx.x, tx = tid & 15, ty = tid >> 4;
    const int m0 = blockIdx.x * 128;
    const int n0 = blockIdx.y * 64;

    float acc[8][4];
#pragma unroll
    for (int i = 0; i < 8; ++i)
#pragma unroll
        for (int j = 0; j < 4; ++j) acc[i][j] = 0.f;

    for (int kt = 0; kt < CDIM; kt += 32) {
        __syncthreads();
#pragma unroll
        for (int it = 0; it < 4; ++it) {
            int idx = tid + 256 * it;
            int row = idx >> 3, c4 = (idx & 7) << 2;
            *(float4*)&As[row * 32 + c4] =
                *(const float4*)&A[(size_t)(m0 + row) * CDIM + kt + c4];
        }
#pragma unroll
        for (int it = 0; it < 2; ++it) {
            int idx = tid + 256 * it;
            int row = idx >> 3, c4 = (idx & 7) << 2;
            *(float4*)&Bs[row * 32 + c4] =
                *(const float4*)&W[(size_t)(n0 + row) * CDIM + kt + c4];
        }
        __syncthreads();
        const float4* As4 = (const float4*)As;
        const float4* Bs4 = (const float4*)Bs;
#pragma unroll
        for (int kq = 0; kq < 8; ++kq) {
            const int ke = (kq + tx) & 7;
            float4 a[8], b[4];
#pragma unroll
            for (int i = 0; i < 8; ++i) a[i] = As4[(ty * 8 + i) * 8 + ke];
#pragma unroll
            for (int j = 0; j < 4; ++j) b[j] = Bs4[(tx * 4 + j) * 8 + ke];
#pragma unroll
            for (int i = 0; i < 8; ++i)
#pragma unroll
                for (int j = 0; j < 4; ++j) {
                    acc[i][j] = fmaf(a[i].x, b[j].x, acc[i][j]);
                    acc[i][j] = fmaf(a[i].y, b[j].y, acc[i][j]);
                    acc[i][j] = fmaf(a[i].z, b[j].z, acc[i][j]);
                    acc[i][j] = fmaf(a[i].w, b[j].w, acc[i][j]);
                }
        }
    }

    float4 bb = *(const float4*)&bias[n0 + tx * 4];
#pragma unroll
    for (int i = 0; i < 8; ++i) {
        size_t m = (size_t)(m0 + ty * 8 + i);
        *(float4*)&out[m * CDIM + n0 + tx * 4] =
            make_float4(acc[i][0] + bb.x, acc[i][1] + bb.y,
                        acc[i][2] + bb.z, acc[i][3] + bb.w);
    }
}

// ---------------------------------------------------------------------------
extern "C" void kernel_launch(void* const* d_in, const int* in_sizes, int n_in,
                              void* d_out, int out_size, void* d_ws,
                              size_t ws_size, hipStream_t stream)
{
    const float* X     = (const float*)d_in[0];   // [2, 2048, 768]
    const float* Wqkv  = (const float*)d_in[1];   // [2304, 768]
    const float* Wproj = (const float*)d_in[2];   // [768, 768]
    const float* bias  = (const float*)d_in[3];   // [768]
    float* out = (float*)d_out;                   // [2, 2048, 768]

    const size_t per_buf = (size_t)NB * NH * NSEQ * HD;  // 3145728 elems
    float* Qb = (float*)d_ws;
    float* Kb = Qb + per_buf;
    float* Vb = Kb + per_buf;
    float* AO = Vb + per_buf;                     // [4096, 768]

    qkv_rope_kernel<<<dim3(32, 18), 256, 0, stream>>>(X, Wqkv, Qb, Kb, Vb);
    attn_kernel<<<dim3(32, 24), 256, 0, stream>>>(Qb, Kb, Vb, AO);
    proj_kernel<<<dim3(32, 12), 256, 0, stream>>>(AO, Wproj, bias, out);
}